// Round 16
// baseline (789.196 us; speedup 1.0000x reference)
//
#include <hip/hip_runtime.h>
#include <hip/hip_fp16.h>
#include <math.h>

static constexpr int NN = 100000;   // nodes
static constexpr int NE = 1600000;  // edges
static constexpr int BUCK_SH = 5;   // 32 nodes per bucket
static constexpr int NBUK = NN >> BUCK_SH;   // 3125 (exact)
static constexpr int NCH = 256;              // chunks (one scat block each)
static constexpr int CH = NE / NCH;          // 6250 edges per chunk (exact)

// pass 1: per-chunk bucket histogram H[chunk][bucket]; block 0 also zeroes the
// degree histogram dh (stream order guarantees this precedes k_blocal).
__global__ __launch_bounds__(256)
void k_chist(const int* __restrict__ ei, int* __restrict__ H, int* __restrict__ dh) {
  __shared__ int h[NBUK];
  if (blockIdx.x == 0) dh[threadIdx.x] = 0;
  for (int i = threadIdx.x; i < NBUK; i += 256) h[i] = 0;
  __syncthreads();
  int chunk = blockIdx.x;
  int start = chunk * CH;
  for (int e = start + threadIdx.x; e < start + CH; e += 256)
    atomicAdd(&h[ei[NE + e] >> BUCK_SH], 1);
  __syncthreads();
  int* Hc = H + chunk * NBUK;
  for (int i = threadIdx.x; i < NBUK; i += 256) Hc[i] = h[i];
}

// pass 2: in-place exclusive prefix over chunks per bucket; totals -> tot
__global__ void k_csum(int* __restrict__ H, int* __restrict__ tot) {
  int b = blockIdx.x * blockDim.x + threadIdx.x;
  if (b >= NBUK) return;
  int acc = 0;
#pragma unroll 4
  for (int c = 0; c < NCH; ++c) {
    int v = H[c * NBUK + b];
    H[c * NBUK + b] = acc;
    acc += v;
  }
  tot[b] = acc;
}

// single-block scan of bucket totals -> boff (exclusive), boff[NBUK]=NE
__global__ __launch_bounds__(1024)
void k_bscan(const int* __restrict__ tot, int* __restrict__ boff) {
  __shared__ int buf[1024];
  __shared__ int s_carry;
  int tid = threadIdx.x;
  if (tid == 0) s_carry = 0;
  __syncthreads();
  for (int base = 0; base < NBUK; base += 1024) {
    int i = base + tid;
    int v = (i < NBUK) ? tot[i] : 0;
    buf[tid] = v;
    __syncthreads();
#pragma unroll
    for (int off = 1; off < 1024; off <<= 1) {
      int t = (tid >= off) ? buf[tid - off] : 0;
      __syncthreads();
      buf[tid] += t;
      __syncthreads();
    }
    int excl = buf[tid] - v;
    int carry = s_carry;
    if (i < NBUK) boff[i] = carry + excl;
    __syncthreads();
    if (tid == 1023) s_carry = carry + buf[1023];
    __syncthreads();
  }
  if (tid == 0) boff[NBUK] = s_carry;   // == NE
}

// pass 3: one block per chunk; LDS cursors; write packed (dstLow5,src) u32
__global__ __launch_bounds__(1024)
void k_scat(const int* __restrict__ ei, const int* __restrict__ H,
            const int* __restrict__ boff, unsigned* __restrict__ se) {
  __shared__ int cur[NBUK];
  int chunk = blockIdx.x;
  const int* Hc = H + chunk * NBUK;
  for (int i = threadIdx.x; i < NBUK; i += 1024) cur[i] = boff[i] + Hc[i];
  __syncthreads();
  int start = chunk * CH;
  for (int e = start + threadIdx.x; e < start + CH; e += 1024) {
    int src = ei[e], dst = ei[NE + e];
    int pos = atomicAdd(&cur[dst >> BUCK_SH], 1);
    se[pos] = ((unsigned)(dst & 31) << 20) | (unsigned)src;   // src < 2^17
  }
}

// one block per bucket: local counting sort -> rowptr, dis, csr_src, deg + dh
__global__ __launch_bounds__(256)
void k_blocal(const unsigned* __restrict__ se, const int* __restrict__ boff,
              int* __restrict__ rowptr, float* __restrict__ dis, int* __restrict__ csr_src,
              int* __restrict__ deg, int* __restrict__ dh) {
  int b = blockIdx.x;
  int base = boff[b], end = boff[b + 1];
  __shared__ int cnt[32], off[32];
  int tid = threadIdx.x;
  if (tid < 32) cnt[tid] = 0;
  __syncthreads();
  for (int k = base + tid; k < end; k += 256)
    atomicAdd(&cnt[se[k] >> 20], 1);
  __syncthreads();
  if (tid == 0) {
    int acc = 0;
#pragma unroll
    for (int i = 0; i < 32; ++i) { off[i] = acc; acc += cnt[i]; }
  }
  __syncthreads();
  if (tid < 32) {
    int node = (b << BUCK_SH) + tid;
    rowptr[node] = base + off[tid];
    dis[node] = rsqrtf(1.0f + (float)cnt[tid]);
    int d = cnt[tid] > 255 ? 255 : cnt[tid];
    deg[node] = d;
    atomicAdd(&dh[d], 1);
    cnt[tid] = 0;                       // reuse as cursor
  }
  if (b == 0 && tid == 64) rowptr[NN] = NE;
  __syncthreads();
  for (int k = base + tid; k < end; k += 256) {
    unsigned e = se[k];
    int dl = e >> 20;
    int pos = base + off[dl] + atomicAdd(&cnt[dl], 1);
    csr_src[pos] = (int)(e & 0xFFFFFu);
  }
}

// exclusive scan of the 256 degree bins -> dcur (fill cursors)
__global__ __launch_bounds__(256)
void k_dscan(const int* __restrict__ dh, int* __restrict__ dcur) {
  __shared__ int buf[256];
  int tid = threadIdx.x;
  int v = dh[tid];
  buf[tid] = v;
  __syncthreads();
#pragma unroll
  for (int off = 1; off < 256; off <<= 1) {
    int t = (tid >= off) ? buf[tid - off] : 0;
    __syncthreads();
    buf[tid] += t;
    __syncthreads();
  }
  dcur[tid] = buf[tid] - v;
}

// perm[pos] = node, pos grouped by degree -> waves get equal-degree nodes
__global__ void k_dperm(const int* __restrict__ deg, int* __restrict__ dcur,
                        int* __restrict__ perm) {
  int i = blockIdx.x * blockDim.x + threadIdx.x;
  if (i >= NN) return;
  int pos = atomicAdd(&dcur[deg[i]], 1);
  perm[pos] = i;
}

// GEMM 64->64 (fp32 in), fp16 out. W-column in registers; rows staged in LDS.
__global__ __launch_bounds__(256)
void k_gemm64_h(const float* __restrict__ in, const float* __restrict__ W,
                const float* __restrict__ dis, __half* __restrict__ g) {
  __shared__ float rows[16 * 64];      // 4 KB
  int c = threadIdx.x & 63;
  int wid = threadIdx.x >> 6;          // 4 waves/block
  float Wc[64];
#pragma unroll
  for (int k = 0; k < 64; ++k) Wc[k] = W[k * 64 + c];
  int tiles = NN / 16;                 // 6250
  for (int t = blockIdx.x; t < tiles; t += gridDim.x) {
    int row0 = t * 16;
    __syncthreads();
    ((float4*)rows)[threadIdx.x] = ((const float4*)(in + (size_t)row0 * 64))[threadIdx.x];
    __syncthreads();
#pragma unroll
    for (int r = 0; r < 4; ++r) {
      const float* rp = rows + (wid * 4 + r) * 64;
      float acc = 0.f;
#pragma unroll
      for (int kc = 0; kc < 64; kc += 4) {
        float4 v = *(const float4*)(rp + kc);   // broadcast ds_read_b128
        acc = fmaf(v.x, Wc[kc + 0], acc);
        acc = fmaf(v.y, Wc[kc + 1], acc);
        acc = fmaf(v.z, Wc[kc + 2], acc);
        acc = fmaf(v.w, Wc[kc + 3], acc);
      }
      int row = row0 + wid * 4 + r;
      g[row * 64 + c] = __float2half(acc * dis[row]);
    }
  }
}

// fast tanh: 1 - 2/(e^{2x}+1); saturates correctly
__device__ __forceinline__ float fast_tanh(float x) {
  float e = __expf(2.0f * x);
  return 1.0f - 2.0f / (e + 1.0f);
}

// unpack 8 fp16 (in a float4) and add into two float4 accumulators
__device__ __forceinline__ void upadd8(float4 r, float4& lo, float4& hi) {
  __half2* h = (__half2*)&r;
  float2 f0 = __half22float2(h[0]);
  float2 f1 = __half22float2(h[1]);
  float2 f2 = __half22float2(h[2]);
  float2 f3 = __half22float2(h[3]);
  lo.x += f0.x; lo.y += f0.y; lo.z += f1.x; lo.w += f1.y;
  hi.x += f2.x; hi.y += f2.y; hi.z += f3.x; hi.w += f3.y;
}

// Layer-1 aggregation FUSED with layer-2 GEMM; nodes taken via degree-sorted
// perm so the 8 groups of a wave have near-equal degree (kills divergence).
__global__ __launch_bounds__(256)
void k_agg64f(const int* __restrict__ rowptr, const int* __restrict__ csr_src,
              const __half* __restrict__ g, const float* __restrict__ dis,
              const float* __restrict__ b, const float* __restrict__ W2,
              const int* __restrict__ perm, __half* __restrict__ g2) {
  __shared__ float tile[4][8][68];     // padded stride
  int lane = threadIdx.x & 63;
  int wid = threadIdx.x >> 6;
  int grp = lane >> 3;                 // node slot 0..7
  int cl = lane & 7;                   // channel octet: ch cl*8..cl*8+7
  int gid = blockIdx.x * 32 + wid * 8 + grp;
  int node = perm[gid];

  // W2 column segment for the epilogue
  int c2 = lane & 31;                  // output column 0..31
  int ksub = lane >> 5;                // K-half 0/1
  float Wc[32];
#pragma unroll
  for (int k = 0; k < 32; ++k) Wc[k] = W2[(ksub * 32 + k) * 32 + c2];

  const char* base = (const char*)g;
  float4 l0 = {0,0,0,0}, h0 = {0,0,0,0}, l1 = {0,0,0,0}, h1 = {0,0,0,0};
  float4 l2 = {0,0,0,0}, h2 = {0,0,0,0}, l3 = {0,0,0,0}, h3 = {0,0,0,0};
  {                                    // self loop
    float4 r = *(const float4*)(base + (size_t)node * 128 + cl * 16);
    upadd8(r, l0, h0);
  }
  int k = rowptr[node], end = rowptr[node + 1];
  for (; k + 4 <= end; k += 4) {
    int s0 = csr_src[k], s1 = csr_src[k + 1], s2 = csr_src[k + 2], s3 = csr_src[k + 3];
    float4 r0 = *(const float4*)(base + (size_t)s0 * 128 + cl * 16);
    float4 r1 = *(const float4*)(base + (size_t)s1 * 128 + cl * 16);
    float4 r2 = *(const float4*)(base + (size_t)s2 * 128 + cl * 16);
    float4 r3 = *(const float4*)(base + (size_t)s3 * 128 + cl * 16);
    upadd8(r0, l0, h0); upadd8(r1, l1, h1);
    upadd8(r2, l2, h2); upadd8(r3, l3, h3);
  }
  for (; k < end; ++k) {
    float4 r = *(const float4*)(base + (size_t)csr_src[k] * 128 + cl * 16);
    upadd8(r, l0, h0);
  }
  float d = dis[node];
  float4 blo = *(const float4*)(b + cl * 8);
  float4 bhi = *(const float4*)(b + cl * 8 + 4);
  float4 vl, vh;
  vl.x = ((l0.x + l1.x) + (l2.x + l3.x)) * d + blo.x;
  vl.y = ((l0.y + l1.y) + (l2.y + l3.y)) * d + blo.y;
  vl.z = ((l0.z + l1.z) + (l2.z + l3.z)) * d + blo.z;
  vl.w = ((l0.w + l1.w) + (l2.w + l3.w)) * d + blo.w;
  vh.x = ((h0.x + h1.x) + (h2.x + h3.x)) * d + bhi.x;
  vh.y = ((h0.y + h1.y) + (h2.y + h3.y)) * d + bhi.y;
  vh.z = ((h0.z + h1.z) + (h2.z + h3.z)) * d + bhi.z;
  vh.w = ((h0.w + h1.w) + (h2.w + h3.w)) * d + bhi.w;
  vl.x = fast_tanh(vl.x); vl.y = fast_tanh(vl.y);
  vl.z = fast_tanh(vl.z); vl.w = fast_tanh(vl.w);
  vh.x = fast_tanh(vh.x); vh.y = fast_tanh(vh.y);
  vh.z = fast_tanh(vh.z); vh.w = fast_tanh(vh.w);

  // stash h1 tile in this wave's own LDS region (no barrier needed)
  *(float4*)&tile[wid][grp][cl * 8] = vl;
  *(float4*)&tile[wid][grp][cl * 8 + 4] = vh;

  // layer-2 GEMM on the wave's own 8 rows (rows scattered via perm)
  int rbase = blockIdx.x * 32 + wid * 8;
#pragma unroll
  for (int r = 0; r < 8; ++r) {
    const float* rp = &tile[wid][r][ksub * 32];
    float acc = 0.f;
#pragma unroll
    for (int kc = 0; kc < 32; kc += 4) {
      float4 v = *(const float4*)(rp + kc);
      acc = fmaf(v.x, Wc[kc + 0], acc);
      acc = fmaf(v.y, Wc[kc + 1], acc);
      acc = fmaf(v.z, Wc[kc + 2], acc);
      acc = fmaf(v.w, Wc[kc + 3], acc);
    }
    acc += __shfl_down(acc, 32);       // combine K-halves
    int noder = perm[rbase + r];
    if (ksub == 0) g2[noder * 32 + c2] = __float2half(acc * dis[noder]);
  }
}

// Layer-2 aggregation fused with layer-3 GEMM; degree-sorted perm.
__global__ __launch_bounds__(256)
void k_agg32v(const int* __restrict__ rowptr, const int* __restrict__ csr_src,
              const __half* __restrict__ g, const float* __restrict__ dis,
              const float* __restrict__ b, const float* __restrict__ W3,
              const int* __restrict__ perm, float* __restrict__ Af) {
  int lane = threadIdx.x & 63;
  int grp = lane >> 3;                 // node slot 0..7
  int cl = lane & 7;                   // channel quad: ch cl*4..cl*4+3
  int node = perm[blockIdx.x * 32 + (threadIdx.x >> 6) * 8 + grp];
  const char* base = (const char*)g;
  float4 a0 = {0,0,0,0}, a1 = {0,0,0,0}, a2 = {0,0,0,0}, a3 = {0,0,0,0};
  {                                    // self loop
    float2 r = *(const float2*)(base + (size_t)node * 64 + cl * 8);
    __half2* h = (__half2*)&r;
    float2 f0 = __half22float2(h[0]), f1 = __half22float2(h[1]);
    a0.x += f0.x; a0.y += f0.y; a0.z += f1.x; a0.w += f1.y;
  }
  int k = rowptr[node], end = rowptr[node + 1];
  for (; k + 8 <= end; k += 8) {       // 8 gathers in flight
    float2 r0 = *(const float2*)(base + (size_t)csr_src[k + 0] * 64 + cl * 8);
    float2 r1 = *(const float2*)(base + (size_t)csr_src[k + 1] * 64 + cl * 8);
    float2 r2 = *(const float2*)(base + (size_t)csr_src[k + 2] * 64 + cl * 8);
    float2 r3 = *(const float2*)(base + (size_t)csr_src[k + 3] * 64 + cl * 8);
    float2 r4 = *(const float2*)(base + (size_t)csr_src[k + 4] * 64 + cl * 8);
    float2 r5 = *(const float2*)(base + (size_t)csr_src[k + 5] * 64 + cl * 8);
    float2 r6 = *(const float2*)(base + (size_t)csr_src[k + 6] * 64 + cl * 8);
    float2 r7 = *(const float2*)(base + (size_t)csr_src[k + 7] * 64 + cl * 8);
    __half2* h; float2 f;
    h = (__half2*)&r0; f = __half22float2(h[0]); a0.x += f.x; a0.y += f.y;
    f = __half22float2(h[1]); a0.z += f.x; a0.w += f.y;
    h = (__half2*)&r1; f = __half22float2(h[0]); a1.x += f.x; a1.y += f.y;
    f = __half22float2(h[1]); a1.z += f.x; a1.w += f.y;
    h = (__half2*)&r2; f = __half22float2(h[0]); a2.x += f.x; a2.y += f.y;
    f = __half22float2(h[1]); a2.z += f.x; a2.w += f.y;
    h = (__half2*)&r3; f = __half22float2(h[0]); a3.x += f.x; a3.y += f.y;
    f = __half22float2(h[1]); a3.z += f.x; a3.w += f.y;
    h = (__half2*)&r4; f = __half22float2(h[0]); a0.x += f.x; a0.y += f.y;
    f = __half22float2(h[1]); a0.z += f.x; a0.w += f.y;
    h = (__half2*)&r5; f = __half22float2(h[0]); a1.x += f.x; a1.y += f.y;
    f = __half22float2(h[1]); a1.z += f.x; a1.w += f.y;
    h = (__half2*)&r6; f = __half22float2(h[0]); a2.x += f.x; a2.y += f.y;
    f = __half22float2(h[1]); a2.z += f.x; a2.w += f.y;
    h = (__half2*)&r7; f = __half22float2(h[0]); a3.x += f.x; a3.y += f.y;
    f = __half22float2(h[1]); a3.z += f.x; a3.w += f.y;
  }
  for (; k + 4 <= end; k += 4) {
    float2 r0 = *(const float2*)(base + (size_t)csr_src[k + 0] * 64 + cl * 8);
    float2 r1 = *(const float2*)(base + (size_t)csr_src[k + 1] * 64 + cl * 8);
    float2 r2 = *(const float2*)(base + (size_t)csr_src[k + 2] * 64 + cl * 8);
    float2 r3 = *(const float2*)(base + (size_t)csr_src[k + 3] * 64 + cl * 8);
    __half2* h; float2 f;
    h = (__half2*)&r0; f = __half22float2(h[0]); a0.x += f.x; a0.y += f.y;
    f = __half22float2(h[1]); a0.z += f.x; a0.w += f.y;
    h = (__half2*)&r1; f = __half22float2(h[0]); a1.x += f.x; a1.y += f.y;
    f = __half22float2(h[1]); a1.z += f.x; a1.w += f.y;
    h = (__half2*)&r2; f = __half22float2(h[0]); a2.x += f.x; a2.y += f.y;
    f = __half22float2(h[1]); a2.z += f.x; a2.w += f.y;
    h = (__half2*)&r3; f = __half22float2(h[0]); a3.x += f.x; a3.y += f.y;
    f = __half22float2(h[1]); a3.z += f.x; a3.w += f.y;
  }
  for (; k < end; ++k) {
    float2 r = *(const float2*)(base + (size_t)csr_src[k] * 64 + cl * 8);
    __half2* h = (__half2*)&r;
    float2 f0 = __half22float2(h[0]), f1 = __half22float2(h[1]);
    a0.x += f0.x; a0.y += f0.y; a0.z += f1.x; a0.w += f1.y;
  }
  float d = dis[node];
  float4 bb = *(const float4*)(b + cl * 4);
  float4 v;
  v.x = ((a0.x + a1.x) + (a2.x + a3.x)) * d + bb.x;
  v.y = ((a0.y + a1.y) + (a2.y + a3.y)) * d + bb.y;
  v.z = ((a0.z + a1.z) + (a2.z + a3.z)) * d + bb.z;
  v.w = ((a0.w + a1.w) + (a2.w + a3.w)) * d + bb.w;
  v.x = fast_tanh(v.x); v.y = fast_tanh(v.y);
  v.z = fast_tanh(v.z); v.w = fast_tanh(v.w);
  // layer-3 message: dot(h2_row, W3) * dis
  float4 w3 = *(const float4*)(W3 + cl * 4);
  float p = v.x * w3.x + v.y * w3.y + v.z * w3.z + v.w * w3.w;
  p += __shfl_xor(p, 1);
  p += __shfl_xor(p, 2);
  p += __shfl_xor(p, 4);
  if (cl == 0) Af[node] = p * d;
}

// C=1: thread per node via perm (degree-balanced waves), fp32.
__global__ void k_agg1(const int* __restrict__ rowptr, const int* __restrict__ csr_src,
                       const float* __restrict__ g, const float* __restrict__ dis,
                       const float* __restrict__ b, const int* __restrict__ perm,
                       float* __restrict__ out) {
  int i = blockIdx.x * blockDim.x + threadIdx.x;
  if (i >= NN) return;
  int node = perm[i];
  float a0 = g[node], a1 = 0.f, a2 = 0.f, a3 = 0.f;
  int beg = rowptr[node], end = rowptr[node + 1];
  int k = beg;
  for (; k + 4 <= end; k += 4) {
    float m0 = g[csr_src[k]], m1 = g[csr_src[k + 1]];
    float m2 = g[csr_src[k + 2]], m3 = g[csr_src[k + 3]];
    a0 += m0; a1 += m1; a2 += m2; a3 += m3;
  }
  for (; k < end; ++k) a0 += g[csr_src[k]];
  out[node] = ((a0 + a1) + (a2 + a3)) * dis[node] + b[0];
}

extern "C" void kernel_launch(void* const* d_in, const int* in_sizes, int n_in,
                              void* d_out, int out_size, void* d_ws, size_t ws_size,
                              hipStream_t stream) {
  const float* x  = (const float*)d_in[0];
  const int*   ei = (const int*)d_in[1];
  const float* W1 = (const float*)d_in[2];
  const float* b1 = (const float*)d_in[3];
  const float* W2 = (const float*)d_in[4];
  const float* b2 = (const float*)d_in[5];
  const float* W3 = (const float*)d_in[6];
  const float* b3 = (const float*)d_in[7];
  float* out = (float*)d_out;

  char* ws = (char*)d_ws;
  int*      H       = (int*)ws;      ws += (size_t)NCH * NBUK * 4;          // 3.2 MB
  int*      tot     = (int*)ws;      ws += ((NBUK + 255)/256)*256 * 4;
  int*      boff    = (int*)ws;      ws += ((NBUK + 1 + 255)/256)*256 * 4;
  unsigned* se      = (unsigned*)ws; ws += (size_t)NE * 4;                  // 6.4 MB
  int*      rowptr  = (int*)ws;      ws += ((NN + 1 + 255)/256)*256 * 4;
  int*      csr_src = (int*)ws;      ws += (size_t)NE * 4;                  // 6.4 MB
  float*    dis     = (float*)ws;    ws += ((NN + 255)/256)*256 * 4;
  int*      deg     = (int*)ws;      ws += ((NN + 255)/256)*256 * 4;
  int*      perm    = (int*)ws;      ws += ((NN + 255)/256)*256 * 4;
  int*      dh      = (int*)ws;      ws += 256 * 4;
  int*      dcur    = (int*)ws;      ws += 256 * 4;
  __half*   Ah      = (__half*)ws;   ws += (size_t)NN * 64 * 2;             // 12.8 MB L1 msgs
  __half*   Ah2     = (__half*)ws;   ws += (size_t)NN * 32 * 2;             // 6.4 MB L2 msgs
  float*    Af      = (float*)ws;    ws += (size_t)NN * 4;                  // 400 KB L3 msgs

  // ---- CSR build (deterministic two-pass counting sort) + dis + degree perm
  k_chist <<<NCH, 256, 0, stream>>>(ei, H, dh);
  k_csum  <<<(NBUK + 255) / 256, 256, 0, stream>>>(H, tot);
  k_bscan <<<1, 1024, 0, stream>>>(tot, boff);
  k_scat  <<<NCH, 1024, 0, stream>>>(ei, H, boff, se);
  k_blocal<<<NBUK, 256, 0, stream>>>(se, boff, rowptr, dis, csr_src, deg, dh);
  k_dscan <<<1, 256, 0, stream>>>(dh, dcur);
  k_dperm <<<(NN + 255) / 256, 256, 0, stream>>>(deg, dcur, perm);

  // ---- layer 1 GEMM: x @ W1 scaled -> fp16 messages
  k_gemm64_h<<<1250, 256, 0, stream>>>(x, W1, dis, Ah);
  // ---- layer-1 aggregation + tanh + FUSED layer-2 GEMM -> fp16 L2 messages
  k_agg64f<<<NN / 32, 256, 0, stream>>>(rowptr, csr_src, Ah, dis, b1, W2, perm, Ah2);
  // ---- layer-2 aggregation + tanh + FUSED layer-3 GEMM -> fp32 L3 messages
  k_agg32v<<<NN / 32, 256, 0, stream>>>(rowptr, csr_src, Ah2, dis, b2, W3, perm, Af);
  // ---- layer-3 aggregation -> d_out
  k_agg1<<<(NN + 255) / 256, 256, 0, stream>>>(rowptr, csr_src, Af, dis, b3, perm, out);
}

// Round 17
// 277.508 us; speedup vs baseline: 2.8439x; 2.8439x over previous
//
#include <hip/hip_runtime.h>
#include <hip/hip_fp16.h>
#include <math.h>

static constexpr int NN = 100000;   // nodes
static constexpr int NE = 1600000;  // edges
static constexpr int BUCK_SH = 5;   // 32 nodes per bucket
static constexpr int NBUK = NN >> BUCK_SH;   // 3125 (exact)
static constexpr int NCH = 256;              // chunks (one scat block each)
static constexpr int CH = NE / NCH;          // 6250 edges per chunk (exact)
static constexpr int NDC = 64;               // degree-sort chunks
static constexpr int DCH = (NN + NDC - 1) / NDC;  // 1563 nodes per chunk

// pass 1: per-chunk bucket histogram H[chunk][bucket] (plain store)
__global__ __launch_bounds__(256)
void k_chist(const int* __restrict__ ei, int* __restrict__ H) {
  __shared__ int h[NBUK];
  for (int i = threadIdx.x; i < NBUK; i += 256) h[i] = 0;
  __syncthreads();
  int chunk = blockIdx.x;
  int start = chunk * CH;
  for (int e = start + threadIdx.x; e < start + CH; e += 256)
    atomicAdd(&h[ei[NE + e] >> BUCK_SH], 1);
  __syncthreads();
  int* Hc = H + chunk * NBUK;
  for (int i = threadIdx.x; i < NBUK; i += 256) Hc[i] = h[i];
}

// pass 2: in-place exclusive prefix over chunks per bucket; totals -> tot
__global__ void k_csum(int* __restrict__ H, int* __restrict__ tot) {
  int b = blockIdx.x * blockDim.x + threadIdx.x;
  if (b >= NBUK) return;
  int acc = 0;
#pragma unroll 4
  for (int c = 0; c < NCH; ++c) {
    int v = H[c * NBUK + b];
    H[c * NBUK + b] = acc;
    acc += v;
  }
  tot[b] = acc;
}

// single-block scan of bucket totals -> boff (exclusive), boff[NBUK]=NE
__global__ __launch_bounds__(1024)
void k_bscan(const int* __restrict__ tot, int* __restrict__ boff) {
  __shared__ int buf[1024];
  __shared__ int s_carry;
  int tid = threadIdx.x;
  if (tid == 0) s_carry = 0;
  __syncthreads();
  for (int base = 0; base < NBUK; base += 1024) {
    int i = base + tid;
    int v = (i < NBUK) ? tot[i] : 0;
    buf[tid] = v;
    __syncthreads();
#pragma unroll
    for (int off = 1; off < 1024; off <<= 1) {
      int t = (tid >= off) ? buf[tid - off] : 0;
      __syncthreads();
      buf[tid] += t;
      __syncthreads();
    }
    int excl = buf[tid] - v;
    int carry = s_carry;
    if (i < NBUK) boff[i] = carry + excl;
    __syncthreads();
    if (tid == 1023) s_carry = carry + buf[1023];
    __syncthreads();
  }
  if (tid == 0) boff[NBUK] = s_carry;   // == NE
}

// pass 3: one block per chunk; LDS cursors; write packed (dstLow5,src) u32
__global__ __launch_bounds__(1024)
void k_scat(const int* __restrict__ ei, const int* __restrict__ H,
            const int* __restrict__ boff, unsigned* __restrict__ se) {
  __shared__ int cur[NBUK];
  int chunk = blockIdx.x;
  const int* Hc = H + chunk * NBUK;
  for (int i = threadIdx.x; i < NBUK; i += 1024) cur[i] = boff[i] + Hc[i];
  __syncthreads();
  int start = chunk * CH;
  for (int e = start + threadIdx.x; e < start + CH; e += 1024) {
    int src = ei[e], dst = ei[NE + e];
    int pos = atomicAdd(&cur[dst >> BUCK_SH], 1);
    se[pos] = ((unsigned)(dst & 31) << 20) | (unsigned)src;   // src < 2^17
  }
}

// one block per bucket: local counting sort -> rowptr, dis, csr_src, deg (plain)
__global__ __launch_bounds__(256)
void k_blocal(const unsigned* __restrict__ se, const int* __restrict__ boff,
              int* __restrict__ rowptr, float* __restrict__ dis, int* __restrict__ csr_src,
              int* __restrict__ deg) {
  int b = blockIdx.x;
  int base = boff[b], end = boff[b + 1];
  __shared__ int cnt[32], off[32];
  int tid = threadIdx.x;
  if (tid < 32) cnt[tid] = 0;
  __syncthreads();
  for (int k = base + tid; k < end; k += 256)
    atomicAdd(&cnt[se[k] >> 20], 1);
  __syncthreads();
  if (tid == 0) {
    int acc = 0;
#pragma unroll
    for (int i = 0; i < 32; ++i) { off[i] = acc; acc += cnt[i]; }
  }
  __syncthreads();
  if (tid < 32) {
    int node = (b << BUCK_SH) + tid;
    rowptr[node] = base + off[tid];
    dis[node] = rsqrtf(1.0f + (float)cnt[tid]);
    deg[node] = cnt[tid] > 255 ? 255 : cnt[tid];   // plain store, no atomics
    cnt[tid] = 0;                       // reuse as cursor
  }
  if (b == 0 && tid == 64) rowptr[NN] = NE;
  __syncthreads();
  for (int k = base + tid; k < end; k += 256) {
    unsigned e = se[k];
    int dl = e >> 20;
    int pos = base + off[dl] + atomicAdd(&cnt[dl], 1);
    csr_src[pos] = (int)(e & 0xFFFFFu);
  }
}

// degree-sort pass 1: per-chunk 256-bin LDS histogram -> Hd[chunk][256]
__global__ __launch_bounds__(256)
void k_dhist(const int* __restrict__ deg, int* __restrict__ Hd) {
  __shared__ int h[256];
  h[threadIdx.x] = 0;
  __syncthreads();
  int start = blockIdx.x * DCH;
  int endn = start + DCH < NN ? start + DCH : NN;
  for (int i = start + threadIdx.x; i < endn; i += 256)
    atomicAdd(&h[deg[i]], 1);
  __syncthreads();
  Hd[blockIdx.x * 256 + threadIdx.x] = h[threadIdx.x];
}

// degree-sort pass 2: per-bin exclusive prefix over chunks + bin scan -> dbase
__global__ __launch_bounds__(256)
void k_dsum(int* __restrict__ Hd, int* __restrict__ dbase) {
  __shared__ int buf[256];
  int b = threadIdx.x;
  int acc = 0;
#pragma unroll 4
  for (int c = 0; c < NDC; ++c) {
    int v = Hd[c * 256 + b];
    Hd[c * 256 + b] = acc;
    acc += v;
  }
  buf[b] = acc;
  __syncthreads();
#pragma unroll
  for (int off = 1; off < 256; off <<= 1) {
    int t = (b >= off) ? buf[b - off] : 0;
    __syncthreads();
    buf[b] += t;
    __syncthreads();
  }
  dbase[b] = buf[b] - acc;             // exclusive over bins
}

// degree-sort pass 3: one block per chunk, LDS cursors -> perm (grouped by deg)
__global__ __launch_bounds__(256)
void k_dfill(const int* __restrict__ deg, const int* __restrict__ Hd,
             const int* __restrict__ dbase, int* __restrict__ perm) {
  __shared__ int cur[256];
  int c = blockIdx.x;
  cur[threadIdx.x] = dbase[threadIdx.x] + Hd[c * 256 + threadIdx.x];
  __syncthreads();
  int start = c * DCH;
  int endn = start + DCH < NN ? start + DCH : NN;
  for (int i = start + threadIdx.x; i < endn; i += 256) {
    int pos = atomicAdd(&cur[deg[i]], 1);   // LDS atomic: cheap
    perm[pos] = i;
  }
}

// GEMM 64->64 (fp32 in), fp16 out. W-column in registers; rows staged in LDS.
__global__ __launch_bounds__(256)
void k_gemm64_h(const float* __restrict__ in, const float* __restrict__ W,
                const float* __restrict__ dis, __half* __restrict__ g) {
  __shared__ float rows[16 * 64];      // 4 KB
  int c = threadIdx.x & 63;
  int wid = threadIdx.x >> 6;          // 4 waves/block
  float Wc[64];
#pragma unroll
  for (int k = 0; k < 64; ++k) Wc[k] = W[k * 64 + c];
  int tiles = NN / 16;                 // 6250
  for (int t = blockIdx.x; t < tiles; t += gridDim.x) {
    int row0 = t * 16;
    __syncthreads();
    ((float4*)rows)[threadIdx.x] = ((const float4*)(in + (size_t)row0 * 64))[threadIdx.x];
    __syncthreads();
#pragma unroll
    for (int r = 0; r < 4; ++r) {
      const float* rp = rows + (wid * 4 + r) * 64;
      float acc = 0.f;
#pragma unroll
      for (int kc = 0; kc < 64; kc += 4) {
        float4 v = *(const float4*)(rp + kc);   // broadcast ds_read_b128
        acc = fmaf(v.x, Wc[kc + 0], acc);
        acc = fmaf(v.y, Wc[kc + 1], acc);
        acc = fmaf(v.z, Wc[kc + 2], acc);
        acc = fmaf(v.w, Wc[kc + 3], acc);
      }
      int row = row0 + wid * 4 + r;
      g[row * 64 + c] = __float2half(acc * dis[row]);
    }
  }
}

// fast tanh: 1 - 2/(e^{2x}+1); saturates correctly
__device__ __forceinline__ float fast_tanh(float x) {
  float e = __expf(2.0f * x);
  return 1.0f - 2.0f / (e + 1.0f);
}

// unpack 8 fp16 (in a float4) and add into two float4 accumulators
__device__ __forceinline__ void upadd8(float4 r, float4& lo, float4& hi) {
  __half2* h = (__half2*)&r;
  float2 f0 = __half22float2(h[0]);
  float2 f1 = __half22float2(h[1]);
  float2 f2 = __half22float2(h[2]);
  float2 f3 = __half22float2(h[3]);
  lo.x += f0.x; lo.y += f0.y; lo.z += f1.x; lo.w += f1.y;
  hi.x += f2.x; hi.y += f2.y; hi.z += f3.x; hi.w += f3.y;
}

// Layer-1 aggregation FUSED with layer-2 GEMM; degree-sorted perm kills
// inter-group degree divergence.
__global__ __launch_bounds__(256)
void k_agg64f(const int* __restrict__ rowptr, const int* __restrict__ csr_src,
              const __half* __restrict__ g, const float* __restrict__ dis,
              const float* __restrict__ b, const float* __restrict__ W2,
              const int* __restrict__ perm, __half* __restrict__ g2) {
  __shared__ float tile[4][8][68];     // padded stride
  int lane = threadIdx.x & 63;
  int wid = threadIdx.x >> 6;
  int grp = lane >> 3;                 // node slot 0..7
  int cl = lane & 7;                   // channel octet: ch cl*8..cl*8+7
  int gid = blockIdx.x * 32 + wid * 8 + grp;
  int node = perm[gid];

  // W2 column segment for the epilogue
  int c2 = lane & 31;                  // output column 0..31
  int ksub = lane >> 5;                // K-half 0/1
  float Wc[32];
#pragma unroll
  for (int k = 0; k < 32; ++k) Wc[k] = W2[(ksub * 32 + k) * 32 + c2];

  const char* base = (const char*)g;
  float4 l0 = {0,0,0,0}, h0 = {0,0,0,0}, l1 = {0,0,0,0}, h1 = {0,0,0,0};
  float4 l2 = {0,0,0,0}, h2 = {0,0,0,0}, l3 = {0,0,0,0}, h3 = {0,0,0,0};
  {                                    // self loop
    float4 r = *(const float4*)(base + (size_t)node * 128 + cl * 16);
    upadd8(r, l0, h0);
  }
  int k = rowptr[node], end = rowptr[node + 1];
  for (; k + 4 <= end; k += 4) {
    int s0 = csr_src[k], s1 = csr_src[k + 1], s2 = csr_src[k + 2], s3 = csr_src[k + 3];
    float4 r0 = *(const float4*)(base + (size_t)s0 * 128 + cl * 16);
    float4 r1 = *(const float4*)(base + (size_t)s1 * 128 + cl * 16);
    float4 r2 = *(const float4*)(base + (size_t)s2 * 128 + cl * 16);
    float4 r3 = *(const float4*)(base + (size_t)s3 * 128 + cl * 16);
    upadd8(r0, l0, h0); upadd8(r1, l1, h1);
    upadd8(r2, l2, h2); upadd8(r3, l3, h3);
  }
  for (; k < end; ++k) {
    float4 r = *(const float4*)(base + (size_t)csr_src[k] * 128 + cl * 16);
    upadd8(r, l0, h0);
  }
  float d = dis[node];
  float4 blo = *(const float4*)(b + cl * 8);
  float4 bhi = *(const float4*)(b + cl * 8 + 4);
  float4 vl, vh;
  vl.x = ((l0.x + l1.x) + (l2.x + l3.x)) * d + blo.x;
  vl.y = ((l0.y + l1.y) + (l2.y + l3.y)) * d + blo.y;
  vl.z = ((l0.z + l1.z) + (l2.z + l3.z)) * d + blo.z;
  vl.w = ((l0.w + l1.w) + (l2.w + l3.w)) * d + blo.w;
  vh.x = ((h0.x + h1.x) + (h2.x + h3.x)) * d + bhi.x;
  vh.y = ((h0.y + h1.y) + (h2.y + h3.y)) * d + bhi.y;
  vh.z = ((h0.z + h1.z) + (h2.z + h3.z)) * d + bhi.z;
  vh.w = ((h0.w + h1.w) + (h2.w + h3.w)) * d + bhi.w;
  vl.x = fast_tanh(vl.x); vl.y = fast_tanh(vl.y);
  vl.z = fast_tanh(vl.z); vl.w = fast_tanh(vl.w);
  vh.x = fast_tanh(vh.x); vh.y = fast_tanh(vh.y);
  vh.z = fast_tanh(vh.z); vh.w = fast_tanh(vh.w);

  // stash h1 tile in this wave's own LDS region (no barrier needed)
  *(float4*)&tile[wid][grp][cl * 8] = vl;
  *(float4*)&tile[wid][grp][cl * 8 + 4] = vh;

  // layer-2 GEMM on the wave's own 8 rows (rows scattered via perm)
  int rbase = blockIdx.x * 32 + wid * 8;
#pragma unroll
  for (int r = 0; r < 8; ++r) {
    const float* rp = &tile[wid][r][ksub * 32];
    float acc = 0.f;
#pragma unroll
    for (int kc = 0; kc < 32; kc += 4) {
      float4 v = *(const float4*)(rp + kc);
      acc = fmaf(v.x, Wc[kc + 0], acc);
      acc = fmaf(v.y, Wc[kc + 1], acc);
      acc = fmaf(v.z, Wc[kc + 2], acc);
      acc = fmaf(v.w, Wc[kc + 3], acc);
    }
    acc += __shfl_down(acc, 32);       // combine K-halves
    int noder = perm[rbase + r];
    if (ksub == 0) g2[noder * 32 + c2] = __float2half(acc * dis[noder]);
  }
}

// Layer-2 aggregation fused with layer-3 GEMM; degree-sorted perm.
__global__ __launch_bounds__(256)
void k_agg32v(const int* __restrict__ rowptr, const int* __restrict__ csr_src,
              const __half* __restrict__ g, const float* __restrict__ dis,
              const float* __restrict__ b, const float* __restrict__ W3,
              const int* __restrict__ perm, float* __restrict__ Af) {
  int lane = threadIdx.x & 63;
  int grp = lane >> 3;                 // node slot 0..7
  int cl = lane & 7;                   // channel quad: ch cl*4..cl*4+3
  int node = perm[blockIdx.x * 32 + (threadIdx.x >> 6) * 8 + grp];
  const char* base = (const char*)g;
  float4 a0 = {0,0,0,0}, a1 = {0,0,0,0}, a2 = {0,0,0,0}, a3 = {0,0,0,0};
  {                                    // self loop
    float2 r = *(const float2*)(base + (size_t)node * 64 + cl * 8);
    __half2* h = (__half2*)&r;
    float2 f0 = __half22float2(h[0]), f1 = __half22float2(h[1]);
    a0.x += f0.x; a0.y += f0.y; a0.z += f1.x; a0.w += f1.y;
  }
  int k = rowptr[node], end = rowptr[node + 1];
  for (; k + 8 <= end; k += 8) {       // 8 gathers in flight
    float2 r0 = *(const float2*)(base + (size_t)csr_src[k + 0] * 64 + cl * 8);
    float2 r1 = *(const float2*)(base + (size_t)csr_src[k + 1] * 64 + cl * 8);
    float2 r2 = *(const float2*)(base + (size_t)csr_src[k + 2] * 64 + cl * 8);
    float2 r3 = *(const float2*)(base + (size_t)csr_src[k + 3] * 64 + cl * 8);
    float2 r4 = *(const float2*)(base + (size_t)csr_src[k + 4] * 64 + cl * 8);
    float2 r5 = *(const float2*)(base + (size_t)csr_src[k + 5] * 64 + cl * 8);
    float2 r6 = *(const float2*)(base + (size_t)csr_src[k + 6] * 64 + cl * 8);
    float2 r7 = *(const float2*)(base + (size_t)csr_src[k + 7] * 64 + cl * 8);
    __half2* h; float2 f;
    h = (__half2*)&r0; f = __half22float2(h[0]); a0.x += f.x; a0.y += f.y;
    f = __half22float2(h[1]); a0.z += f.x; a0.w += f.y;
    h = (__half2*)&r1; f = __half22float2(h[0]); a1.x += f.x; a1.y += f.y;
    f = __half22float2(h[1]); a1.z += f.x; a1.w += f.y;
    h = (__half2*)&r2; f = __half22float2(h[0]); a2.x += f.x; a2.y += f.y;
    f = __half22float2(h[1]); a2.z += f.x; a2.w += f.y;
    h = (__half2*)&r3; f = __half22float2(h[0]); a3.x += f.x; a3.y += f.y;
    f = __half22float2(h[1]); a3.z += f.x; a3.w += f.y;
    h = (__half2*)&r4; f = __half22float2(h[0]); a0.x += f.x; a0.y += f.y;
    f = __half22float2(h[1]); a0.z += f.x; a0.w += f.y;
    h = (__half2*)&r5; f = __half22float2(h[0]); a1.x += f.x; a1.y += f.y;
    f = __half22float2(h[1]); a1.z += f.x; a1.w += f.y;
    h = (__half2*)&r6; f = __half22float2(h[0]); a2.x += f.x; a2.y += f.y;
    f = __half22float2(h[1]); a2.z += f.x; a2.w += f.y;
    h = (__half2*)&r7; f = __half22float2(h[0]); a3.x += f.x; a3.y += f.y;
    f = __half22float2(h[1]); a3.z += f.x; a3.w += f.y;
  }
  for (; k + 4 <= end; k += 4) {
    float2 r0 = *(const float2*)(base + (size_t)csr_src[k + 0] * 64 + cl * 8);
    float2 r1 = *(const float2*)(base + (size_t)csr_src[k + 1] * 64 + cl * 8);
    float2 r2 = *(const float2*)(base + (size_t)csr_src[k + 2] * 64 + cl * 8);
    float2 r3 = *(const float2*)(base + (size_t)csr_src[k + 3] * 64 + cl * 8);
    __half2* h; float2 f;
    h = (__half2*)&r0; f = __half22float2(h[0]); a0.x += f.x; a0.y += f.y;
    f = __half22float2(h[1]); a0.z += f.x; a0.w += f.y;
    h = (__half2*)&r1; f = __half22float2(h[0]); a1.x += f.x; a1.y += f.y;
    f = __half22float2(h[1]); a1.z += f.x; a1.w += f.y;
    h = (__half2*)&r2; f = __half22float2(h[0]); a2.x += f.x; a2.y += f.y;
    f = __half22float2(h[1]); a2.z += f.x; a2.w += f.y;
    h = (__half2*)&r3; f = __half22float2(h[0]); a3.x += f.x; a3.y += f.y;
    f = __half22float2(h[1]); a3.z += f.x; a3.w += f.y;
  }
  for (; k < end; ++k) {
    float2 r = *(const float2*)(base + (size_t)csr_src[k] * 64 + cl * 8);
    __half2* h = (__half2*)&r;
    float2 f0 = __half22float2(h[0]), f1 = __half22float2(h[1]);
    a0.x += f0.x; a0.y += f0.y; a0.z += f1.x; a0.w += f1.y;
  }
  float d = dis[node];
  float4 bb = *(const float4*)(b + cl * 4);
  float4 v;
  v.x = ((a0.x + a1.x) + (a2.x + a3.x)) * d + bb.x;
  v.y = ((a0.y + a1.y) + (a2.y + a3.y)) * d + bb.y;
  v.z = ((a0.z + a1.z) + (a2.z + a3.z)) * d + bb.z;
  v.w = ((a0.w + a1.w) + (a2.w + a3.w)) * d + bb.w;
  v.x = fast_tanh(v.x); v.y = fast_tanh(v.y);
  v.z = fast_tanh(v.z); v.w = fast_tanh(v.w);
  // layer-3 message: dot(h2_row, W3) * dis
  float4 w3 = *(const float4*)(W3 + cl * 4);
  float p = v.x * w3.x + v.y * w3.y + v.z * w3.z + v.w * w3.w;
  p += __shfl_xor(p, 1);
  p += __shfl_xor(p, 2);
  p += __shfl_xor(p, 4);
  if (cl == 0) Af[node] = p * d;
}

// C=1: thread per node via perm (degree-balanced waves), fp32.
__global__ void k_agg1(const int* __restrict__ rowptr, const int* __restrict__ csr_src,
                       const float* __restrict__ g, const float* __restrict__ dis,
                       const float* __restrict__ b, const int* __restrict__ perm,
                       float* __restrict__ out) {
  int i = blockIdx.x * blockDim.x + threadIdx.x;
  if (i >= NN) return;
  int node = perm[i];
  float a0 = g[node], a1 = 0.f, a2 = 0.f, a3 = 0.f;
  int beg = rowptr[node], end = rowptr[node + 1];
  int k = beg;
  for (; k + 4 <= end; k += 4) {
    float m0 = g[csr_src[k]], m1 = g[csr_src[k + 1]];
    float m2 = g[csr_src[k + 2]], m3 = g[csr_src[k + 3]];
    a0 += m0; a1 += m1; a2 += m2; a3 += m3;
  }
  for (; k < end; ++k) a0 += g[csr_src[k]];
  out[node] = ((a0 + a1) + (a2 + a3)) * dis[node] + b[0];
}

extern "C" void kernel_launch(void* const* d_in, const int* in_sizes, int n_in,
                              void* d_out, int out_size, void* d_ws, size_t ws_size,
                              hipStream_t stream) {
  const float* x  = (const float*)d_in[0];
  const int*   ei = (const int*)d_in[1];
  const float* W1 = (const float*)d_in[2];
  const float* b1 = (const float*)d_in[3];
  const float* W2 = (const float*)d_in[4];
  const float* b2 = (const float*)d_in[5];
  const float* W3 = (const float*)d_in[6];
  const float* b3 = (const float*)d_in[7];
  float* out = (float*)d_out;

  char* ws = (char*)d_ws;
  int*      H       = (int*)ws;      ws += (size_t)NCH * NBUK * 4;          // 3.2 MB
  int*      tot     = (int*)ws;      ws += ((NBUK + 255)/256)*256 * 4;
  int*      boff    = (int*)ws;      ws += ((NBUK + 1 + 255)/256)*256 * 4;
  unsigned* se      = (unsigned*)ws; ws += (size_t)NE * 4;                  // 6.4 MB
  int*      rowptr  = (int*)ws;      ws += ((NN + 1 + 255)/256)*256 * 4;
  int*      csr_src = (int*)ws;      ws += (size_t)NE * 4;                  // 6.4 MB
  float*    dis     = (float*)ws;    ws += ((NN + 255)/256)*256 * 4;
  int*      deg     = (int*)ws;      ws += ((NN + 255)/256)*256 * 4;
  int*      perm    = (int*)ws;      ws += ((NN + 255)/256)*256 * 4;
  int*      Hd      = (int*)ws;      ws += (size_t)NDC * 256 * 4;           // 64 KB
  int*      dbase   = (int*)ws;      ws += 256 * 4;
  __half*   Ah      = (__half*)ws;   ws += (size_t)NN * 64 * 2;             // 12.8 MB L1 msgs
  __half*   Ah2     = (__half*)ws;   ws += (size_t)NN * 32 * 2;             // 6.4 MB L2 msgs
  float*    Af      = (float*)ws;    ws += (size_t)NN * 4;                  // 400 KB L3 msgs

  // ---- CSR build (deterministic two-pass counting sort) + dis + deg
  k_chist <<<NCH, 256, 0, stream>>>(ei, H);
  k_csum  <<<(NBUK + 255) / 256, 256, 0, stream>>>(H, tot);
  k_bscan <<<1, 1024, 0, stream>>>(tot, boff);
  k_scat  <<<NCH, 1024, 0, stream>>>(ei, H, boff, se);
  k_blocal<<<NBUK, 256, 0, stream>>>(se, boff, rowptr, dis, csr_src, deg);

  // ---- degree-sorted perm (contention-free chunked counting sort)
  k_dhist<<<NDC, 256, 0, stream>>>(deg, Hd);
  k_dsum <<<1, 256, 0, stream>>>(Hd, dbase);
  k_dfill<<<NDC, 256, 0, stream>>>(deg, Hd, dbase, perm);

  // ---- layer 1 GEMM: x @ W1 scaled -> fp16 messages
  k_gemm64_h<<<1250, 256, 0, stream>>>(x, W1, dis, Ah);
  // ---- layer-1 aggregation + tanh + FUSED layer-2 GEMM -> fp16 L2 messages
  k_agg64f<<<NN / 32, 256, 0, stream>>>(rowptr, csr_src, Ah, dis, b1, W2, perm, Ah2);
  // ---- layer-2 aggregation + tanh + FUSED layer-3 GEMM -> fp32 L3 messages
  k_agg32v<<<NN / 32, 256, 0, stream>>>(rowptr, csr_src, Ah2, dis, b2, W3, perm, Af);
  // ---- layer-3 aggregation -> d_out
  k_agg1<<<(NN + 255) / 256, 256, 0, stream>>>(rowptr, csr_src, Af, dis, b3, perm, out);
}

// Round 18
// 250.433 us; speedup vs baseline: 3.1513x; 1.1081x over previous
//
#include <hip/hip_runtime.h>
#include <hip/hip_fp16.h>
#include <math.h>

static constexpr int NN = 100000;   // nodes
static constexpr int NE = 1600000;  // edges
static constexpr int BUCK_SH = 5;   // 32 nodes per bucket
static constexpr int NBUK = NN >> BUCK_SH;   // 3125 (exact)
static constexpr int NCH = 256;              // chunks (one scat block each)
static constexpr int CH = NE / NCH;          // 6250 edges per chunk (exact)

// pass 1: per-chunk bucket histogram H[chunk][bucket] (plain store)
__global__ __launch_bounds__(256)
void k_chist(const int* __restrict__ ei, int* __restrict__ H) {
  __shared__ int h[NBUK];
  for (int i = threadIdx.x; i < NBUK; i += 256) h[i] = 0;
  __syncthreads();
  int chunk = blockIdx.x;
  int start = chunk * CH;
  for (int e = start + threadIdx.x; e < start + CH; e += 256)
    atomicAdd(&h[ei[NE + e] >> BUCK_SH], 1);
  __syncthreads();
  int* Hc = H + chunk * NBUK;
  for (int i = threadIdx.x; i < NBUK; i += 256) Hc[i] = h[i];
}

// pass 2: in-place exclusive prefix over chunks per bucket; totals -> tot
__global__ void k_csum(int* __restrict__ H, int* __restrict__ tot) {
  int b = blockIdx.x * blockDim.x + threadIdx.x;
  if (b >= NBUK) return;
  int acc = 0;
#pragma unroll 4
  for (int c = 0; c < NCH; ++c) {
    int v = H[c * NBUK + b];
    H[c * NBUK + b] = acc;
    acc += v;
  }
  tot[b] = acc;
}

// single-block scan of bucket totals -> boff (exclusive), boff[NBUK]=NE
__global__ __launch_bounds__(1024)
void k_bscan(const int* __restrict__ tot, int* __restrict__ boff) {
  __shared__ int buf[1024];
  __shared__ int s_carry;
  int tid = threadIdx.x;
  if (tid == 0) s_carry = 0;
  __syncthreads();
  for (int base = 0; base < NBUK; base += 1024) {
    int i = base + tid;
    int v = (i < NBUK) ? tot[i] : 0;
    buf[tid] = v;
    __syncthreads();
#pragma unroll
    for (int off = 1; off < 1024; off <<= 1) {
      int t = (tid >= off) ? buf[tid - off] : 0;
      __syncthreads();
      buf[tid] += t;
      __syncthreads();
    }
    int excl = buf[tid] - v;
    int carry = s_carry;
    if (i < NBUK) boff[i] = carry + excl;
    __syncthreads();
    if (tid == 1023) s_carry = carry + buf[1023];
    __syncthreads();
  }
  if (tid == 0) boff[NBUK] = s_carry;   // == NE
}

// pass 3: one block per chunk; LDS cursors; write packed (dstLow5,src) u32
__global__ __launch_bounds__(1024)
void k_scat(const int* __restrict__ ei, const int* __restrict__ H,
            const int* __restrict__ boff, unsigned* __restrict__ se) {
  __shared__ int cur[NBUK];
  int chunk = blockIdx.x;
  const int* Hc = H + chunk * NBUK;
  for (int i = threadIdx.x; i < NBUK; i += 1024) cur[i] = boff[i] + Hc[i];
  __syncthreads();
  int start = chunk * CH;
  for (int e = start + threadIdx.x; e < start + CH; e += 1024) {
    int src = ei[e], dst = ei[NE + e];
    int pos = atomicAdd(&cur[dst >> BUCK_SH], 1);
    se[pos] = ((unsigned)(dst & 31) << 20) | (unsigned)src;   // src < 2^17
  }
}

// one block per bucket: local counting sort -> rowptr, dis, csr_src
__global__ __launch_bounds__(256)
void k_blocal(const unsigned* __restrict__ se, const int* __restrict__ boff,
              int* __restrict__ rowptr, float* __restrict__ dis, int* __restrict__ csr_src) {
  int b = blockIdx.x;
  int base = boff[b], end = boff[b + 1];
  __shared__ int cnt[32], off[32];
  int tid = threadIdx.x;
  if (tid < 32) cnt[tid] = 0;
  __syncthreads();
  for (int k = base + tid; k < end; k += 256)
    atomicAdd(&cnt[se[k] >> 20], 1);
  __syncthreads();
  if (tid == 0) {
    int acc = 0;
#pragma unroll
    for (int i = 0; i < 32; ++i) { off[i] = acc; acc += cnt[i]; }
  }
  __syncthreads();
  if (tid < 32) {
    int node = (b << BUCK_SH) + tid;
    rowptr[node] = base + off[tid];
    dis[node] = rsqrtf(1.0f + (float)cnt[tid]);
    cnt[tid] = 0;                       // reuse as cursor
  }
  if (b == 0 && tid == 64) rowptr[NN] = NE;
  __syncthreads();
  for (int k = base + tid; k < end; k += 256) {
    unsigned e = se[k];
    int dl = e >> 20;
    int pos = base + off[dl] + atomicAdd(&cnt[dl], 1);
    csr_src[pos] = (int)(e & 0xFFFFFu);
  }
}

// GEMM 64->64 (fp32 in), fp16 out. W-column in registers; rows staged in LDS.
__global__ __launch_bounds__(256)
void k_gemm64_h(const float* __restrict__ in, const float* __restrict__ W,
                const float* __restrict__ dis, __half* __restrict__ g) {
  __shared__ float rows[16 * 64];      // 4 KB
  int c = threadIdx.x & 63;
  int wid = threadIdx.x >> 6;          // 4 waves/block
  float Wc[64];
#pragma unroll
  for (int k = 0; k < 64; ++k) Wc[k] = W[k * 64 + c];
  int tiles = NN / 16;                 // 6250
  for (int t = blockIdx.x; t < tiles; t += gridDim.x) {
    int row0 = t * 16;
    __syncthreads();
    ((float4*)rows)[threadIdx.x] = ((const float4*)(in + (size_t)row0 * 64))[threadIdx.x];
    __syncthreads();
#pragma unroll
    for (int r = 0; r < 4; ++r) {
      const float* rp = rows + (wid * 4 + r) * 64;
      float acc = 0.f;
#pragma unroll
      for (int kc = 0; kc < 64; kc += 4) {
        float4 v = *(const float4*)(rp + kc);   // broadcast ds_read_b128
        acc = fmaf(v.x, Wc[kc + 0], acc);
        acc = fmaf(v.y, Wc[kc + 1], acc);
        acc = fmaf(v.z, Wc[kc + 2], acc);
        acc = fmaf(v.w, Wc[kc + 3], acc);
      }
      int row = row0 + wid * 4 + r;
      g[row * 64 + c] = __float2half(acc * dis[row]);
    }
  }
}

// fast tanh: 1 - 2/(e^{2x}+1); saturates correctly
__device__ __forceinline__ float fast_tanh(float x) {
  float e = __expf(2.0f * x);
  return 1.0f - 2.0f / (e + 1.0f);
}

// unpack 8 fp16 (in a float4) and add into two float4 accumulators
__device__ __forceinline__ void upadd8(float4 r, float4& lo, float4& hi) {
  __half2* h = (__half2*)&r;
  float2 f0 = __half22float2(h[0]);
  float2 f1 = __half22float2(h[1]);
  float2 f2 = __half22float2(h[2]);
  float2 f3 = __half22float2(h[3]);
  lo.x += f0.x; lo.y += f0.y; lo.z += f1.x; lo.w += f1.y;
  hi.x += f2.x; hi.y += f2.y; hi.z += f3.x; hi.w += f3.y;
}

// Layer-1 aggregation FUSED with layer-2 GEMM. 8 nodes/wave, 8 lanes/node,
// float4 (=8 fp16 ch)/lane. 8-DEEP gather (8 loads in flight). h1 via per-wave
// LDS region (no barrier); tile stride padded to 68 floats.
__global__ __launch_bounds__(256)
void k_agg64f(const int* __restrict__ rowptr, const int* __restrict__ csr_src,
              const __half* __restrict__ g, const float* __restrict__ dis,
              const float* __restrict__ b, const float* __restrict__ W2,
              __half* __restrict__ g2) {
  __shared__ float tile[4][8][68];
  int lane = threadIdx.x & 63;
  int wid = threadIdx.x >> 6;
  int grp = lane >> 3;                 // node slot 0..7
  int cl = lane & 7;                   // channel octet: ch cl*8..cl*8+7
  int node = blockIdx.x * 32 + wid * 8 + grp;

  // W2 column segment for the epilogue
  int c2 = lane & 31;                  // output column 0..31
  int ksub = lane >> 5;                // K-half 0/1
  float Wc[32];
#pragma unroll
  for (int k = 0; k < 32; ++k) Wc[k] = W2[(ksub * 32 + k) * 32 + c2];

  const char* base = (const char*)g;
  float4 l0 = {0,0,0,0}, h0 = {0,0,0,0}, l1 = {0,0,0,0}, h1 = {0,0,0,0};
  float4 l2 = {0,0,0,0}, h2 = {0,0,0,0}, l3 = {0,0,0,0}, h3 = {0,0,0,0};
  {                                    // self loop
    float4 r = *(const float4*)(base + (size_t)node * 128 + cl * 16);
    upadd8(r, l0, h0);
  }
  int k = rowptr[node], end = rowptr[node + 1];
  for (; k + 8 <= end; k += 8) {       // 8 gathers in flight
    int s0 = csr_src[k + 0], s1 = csr_src[k + 1], s2 = csr_src[k + 2], s3 = csr_src[k + 3];
    int s4 = csr_src[k + 4], s5 = csr_src[k + 5], s6 = csr_src[k + 6], s7 = csr_src[k + 7];
    float4 r0 = *(const float4*)(base + (size_t)s0 * 128 + cl * 16);
    float4 r1 = *(const float4*)(base + (size_t)s1 * 128 + cl * 16);
    float4 r2 = *(const float4*)(base + (size_t)s2 * 128 + cl * 16);
    float4 r3 = *(const float4*)(base + (size_t)s3 * 128 + cl * 16);
    float4 r4 = *(const float4*)(base + (size_t)s4 * 128 + cl * 16);
    float4 r5 = *(const float4*)(base + (size_t)s5 * 128 + cl * 16);
    float4 r6 = *(const float4*)(base + (size_t)s6 * 128 + cl * 16);
    float4 r7 = *(const float4*)(base + (size_t)s7 * 128 + cl * 16);
    upadd8(r0, l0, h0); upadd8(r1, l1, h1);
    upadd8(r2, l2, h2); upadd8(r3, l3, h3);
    upadd8(r4, l0, h0); upadd8(r5, l1, h1);
    upadd8(r6, l2, h2); upadd8(r7, l3, h3);
  }
  for (; k + 4 <= end; k += 4) {
    int s0 = csr_src[k], s1 = csr_src[k + 1], s2 = csr_src[k + 2], s3 = csr_src[k + 3];
    float4 r0 = *(const float4*)(base + (size_t)s0 * 128 + cl * 16);
    float4 r1 = *(const float4*)(base + (size_t)s1 * 128 + cl * 16);
    float4 r2 = *(const float4*)(base + (size_t)s2 * 128 + cl * 16);
    float4 r3 = *(const float4*)(base + (size_t)s3 * 128 + cl * 16);
    upadd8(r0, l0, h0); upadd8(r1, l1, h1);
    upadd8(r2, l2, h2); upadd8(r3, l3, h3);
  }
  for (; k < end; ++k) {
    float4 r = *(const float4*)(base + (size_t)csr_src[k] * 128 + cl * 16);
    upadd8(r, l0, h0);
  }
  float d = dis[node];
  float4 blo = *(const float4*)(b + cl * 8);
  float4 bhi = *(const float4*)(b + cl * 8 + 4);
  float4 vl, vh;
  vl.x = ((l0.x + l1.x) + (l2.x + l3.x)) * d + blo.x;
  vl.y = ((l0.y + l1.y) + (l2.y + l3.y)) * d + blo.y;
  vl.z = ((l0.z + l1.z) + (l2.z + l3.z)) * d + blo.z;
  vl.w = ((l0.w + l1.w) + (l2.w + l3.w)) * d + blo.w;
  vh.x = ((h0.x + h1.x) + (h2.x + h3.x)) * d + bhi.x;
  vh.y = ((h0.y + h1.y) + (h2.y + h3.y)) * d + bhi.y;
  vh.z = ((h0.z + h1.z) + (h2.z + h3.z)) * d + bhi.z;
  vh.w = ((h0.w + h1.w) + (h2.w + h3.w)) * d + bhi.w;
  vl.x = fast_tanh(vl.x); vl.y = fast_tanh(vl.y);
  vl.z = fast_tanh(vl.z); vl.w = fast_tanh(vl.w);
  vh.x = fast_tanh(vh.x); vh.y = fast_tanh(vh.y);
  vh.z = fast_tanh(vh.z); vh.w = fast_tanh(vh.w);

  // stash h1 tile in this wave's own LDS region (no barrier needed)
  *(float4*)&tile[wid][grp][cl * 8] = vl;
  *(float4*)&tile[wid][grp][cl * 8 + 4] = vh;

  // layer-2 GEMM on the wave's own 8 rows
  int rbase = blockIdx.x * 32 + wid * 8;
#pragma unroll
  for (int r = 0; r < 8; ++r) {
    const float* rp = &tile[wid][r][ksub * 32];
    float acc = 0.f;
#pragma unroll
    for (int kc = 0; kc < 32; kc += 4) {
      float4 v = *(const float4*)(rp + kc);
      acc = fmaf(v.x, Wc[kc + 0], acc);
      acc = fmaf(v.y, Wc[kc + 1], acc);
      acc = fmaf(v.z, Wc[kc + 2], acc);
      acc = fmaf(v.w, Wc[kc + 3], acc);
    }
    acc += __shfl_down(acc, 32);       // combine K-halves
    int row = rbase + r;
    if (ksub == 0) g2[row * 32 + c2] = __float2half(acc * dis[row]);
  }
}

// Layer-2 aggregation fused with layer-3 GEMM: 8 nodes/wave, 8 lanes/node;
// float2 (=4 fp16 ch) per lane; 8-deep MLP. Epilogue: tanh -> h2, dot with W3
// segment, shfl-reduce over the 8-lane group, lane 0 stores (h2.W3)*dis.
__global__ __launch_bounds__(256)
void k_agg32v(const int* __restrict__ rowptr, const int* __restrict__ csr_src,
              const __half* __restrict__ g, const float* __restrict__ dis,
              const float* __restrict__ b, const float* __restrict__ W3,
              float* __restrict__ Af) {
  int lane = threadIdx.x & 63;
  int grp = lane >> 3;                 // node slot 0..7
  int cl = lane & 7;                   // channel quad: ch cl*4..cl*4+3
  int node = blockIdx.x * 32 + (threadIdx.x >> 6) * 8 + grp;
  if (node >= NN) return;
  const char* base = (const char*)g;
  float4 a0 = {0,0,0,0}, a1 = {0,0,0,0}, a2 = {0,0,0,0}, a3 = {0,0,0,0};
  {                                    // self loop
    float2 r = *(const float2*)(base + (size_t)node * 64 + cl * 8);
    __half2* h = (__half2*)&r;
    float2 f0 = __half22float2(h[0]), f1 = __half22float2(h[1]);
    a0.x += f0.x; a0.y += f0.y; a0.z += f1.x; a0.w += f1.y;
  }
  int k = rowptr[node], end = rowptr[node + 1];
  for (; k + 8 <= end; k += 8) {       // 8 gathers in flight
    float2 r0 = *(const float2*)(base + (size_t)csr_src[k + 0] * 64 + cl * 8);
    float2 r1 = *(const float2*)(base + (size_t)csr_src[k + 1] * 64 + cl * 8);
    float2 r2 = *(const float2*)(base + (size_t)csr_src[k + 2] * 64 + cl * 8);
    float2 r3 = *(const float2*)(base + (size_t)csr_src[k + 3] * 64 + cl * 8);
    float2 r4 = *(const float2*)(base + (size_t)csr_src[k + 4] * 64 + cl * 8);
    float2 r5 = *(const float2*)(base + (size_t)csr_src[k + 5] * 64 + cl * 8);
    float2 r6 = *(const float2*)(base + (size_t)csr_src[k + 6] * 64 + cl * 8);
    float2 r7 = *(const float2*)(base + (size_t)csr_src[k + 7] * 64 + cl * 8);
    __half2* h; float2 f;
    h = (__half2*)&r0; f = __half22float2(h[0]); a0.x += f.x; a0.y += f.y;
    f = __half22float2(h[1]); a0.z += f.x; a0.w += f.y;
    h = (__half2*)&r1; f = __half22float2(h[0]); a1.x += f.x; a1.y += f.y;
    f = __half22float2(h[1]); a1.z += f.x; a1.w += f.y;
    h = (__half2*)&r2; f = __half22float2(h[0]); a2.x += f.x; a2.y += f.y;
    f = __half22float2(h[1]); a2.z += f.x; a2.w += f.y;
    h = (__half2*)&r3; f = __half22float2(h[0]); a3.x += f.x; a3.y += f.y;
    f = __half22float2(h[1]); a3.z += f.x; a3.w += f.y;
    h = (__half2*)&r4; f = __half22float2(h[0]); a0.x += f.x; a0.y += f.y;
    f = __half22float2(h[1]); a0.z += f.x; a0.w += f.y;
    h = (__half2*)&r5; f = __half22float2(h[0]); a1.x += f.x; a1.y += f.y;
    f = __half22float2(h[1]); a1.z += f.x; a1.w += f.y;
    h = (__half2*)&r6; f = __half22float2(h[0]); a2.x += f.x; a2.y += f.y;
    f = __half22float2(h[1]); a2.z += f.x; a2.w += f.y;
    h = (__half2*)&r7; f = __half22float2(h[0]); a3.x += f.x; a3.y += f.y;
    f = __half22float2(h[1]); a3.z += f.x; a3.w += f.y;
  }
  for (; k + 4 <= end; k += 4) {
    float2 r0 = *(const float2*)(base + (size_t)csr_src[k + 0] * 64 + cl * 8);
    float2 r1 = *(const float2*)(base + (size_t)csr_src[k + 1] * 64 + cl * 8);
    float2 r2 = *(const float2*)(base + (size_t)csr_src[k + 2] * 64 + cl * 8);
    float2 r3 = *(const float2*)(base + (size_t)csr_src[k + 3] * 64 + cl * 8);
    __half2* h; float2 f;
    h = (__half2*)&r0; f = __half22float2(h[0]); a0.x += f.x; a0.y += f.y;
    f = __half22float2(h[1]); a0.z += f.x; a0.w += f.y;
    h = (__half2*)&r1; f = __half22float2(h[0]); a1.x += f.x; a1.y += f.y;
    f = __half22float2(h[1]); a1.z += f.x; a1.w += f.y;
    h = (__half2*)&r2; f = __half22float2(h[0]); a2.x += f.x; a2.y += f.y;
    f = __half22float2(h[1]); a2.z += f.x; a2.w += f.y;
    h = (__half2*)&r3; f = __half22float2(h[0]); a3.x += f.x; a3.y += f.y;
    f = __half22float2(h[1]); a3.z += f.x; a3.w += f.y;
  }
  for (; k < end; ++k) {
    float2 r = *(const float2*)(base + (size_t)csr_src[k] * 64 + cl * 8);
    __half2* h = (__half2*)&r;
    float2 f0 = __half22float2(h[0]), f1 = __half22float2(h[1]);
    a0.x += f0.x; a0.y += f0.y; a0.z += f1.x; a0.w += f1.y;
  }
  float d = dis[node];
  float4 bb = *(const float4*)(b + cl * 4);
  float4 v;
  v.x = ((a0.x + a1.x) + (a2.x + a3.x)) * d + bb.x;
  v.y = ((a0.y + a1.y) + (a2.y + a3.y)) * d + bb.y;
  v.z = ((a0.z + a1.z) + (a2.z + a3.z)) * d + bb.z;
  v.w = ((a0.w + a1.w) + (a2.w + a3.w)) * d + bb.w;
  v.x = fast_tanh(v.x); v.y = fast_tanh(v.y);
  v.z = fast_tanh(v.z); v.w = fast_tanh(v.w);
  // layer-3 message: dot(h2_row, W3) * dis
  float4 w3 = *(const float4*)(W3 + cl * 4);
  float p = v.x * w3.x + v.y * w3.y + v.z * w3.z + v.w * w3.w;
  p += __shfl_xor(p, 1);
  p += __shfl_xor(p, 2);
  p += __shfl_xor(p, 4);
  if (cl == 0) Af[node] = p * d;
}

// C=1: thread per node, fp32 (tiny).
__global__ void k_agg1(const int* __restrict__ rowptr, const int* __restrict__ csr_src,
                       const float* __restrict__ g, const float* __restrict__ dis,
                       const float* __restrict__ b, float* __restrict__ out) {
  int node = blockIdx.x * blockDim.x + threadIdx.x;
  if (node >= NN) return;
  float a0 = g[node], a1 = 0.f, a2 = 0.f, a3 = 0.f;
  int beg = rowptr[node], end = rowptr[node + 1];
  int k = beg;
  for (; k + 4 <= end; k += 4) {
    float m0 = g[csr_src[k]], m1 = g[csr_src[k + 1]];
    float m2 = g[csr_src[k + 2]], m3 = g[csr_src[k + 3]];
    a0 += m0; a1 += m1; a2 += m2; a3 += m3;
  }
  for (; k < end; ++k) a0 += g[csr_src[k]];
  out[node] = ((a0 + a1) + (a2 + a3)) * dis[node] + b[0];
}

extern "C" void kernel_launch(void* const* d_in, const int* in_sizes, int n_in,
                              void* d_out, int out_size, void* d_ws, size_t ws_size,
                              hipStream_t stream) {
  const float* x  = (const float*)d_in[0];
  const int*   ei = (const int*)d_in[1];
  const float* W1 = (const float*)d_in[2];
  const float* b1 = (const float*)d_in[3];
  const float* W2 = (const float*)d_in[4];
  const float* b2 = (const float*)d_in[5];
  const float* W3 = (const float*)d_in[6];
  const float* b3 = (const float*)d_in[7];
  float* out = (float*)d_out;

  char* ws = (char*)d_ws;
  int*      H       = (int*)ws;      ws += (size_t)NCH * NBUK * 4;          // 3.2 MB
  int*      tot     = (int*)ws;      ws += ((NBUK + 255)/256)*256 * 4;
  int*      boff    = (int*)ws;      ws += ((NBUK + 1 + 255)/256)*256 * 4;
  unsigned* se      = (unsigned*)ws; ws += (size_t)NE * 4;                  // 6.4 MB
  int*      rowptr  = (int*)ws;      ws += ((NN + 1 + 255)/256)*256 * 4;
  int*      csr_src = (int*)ws;      ws += (size_t)NE * 4;                  // 6.4 MB
  float*    dis     = (float*)ws;    ws += ((NN + 255)/256)*256 * 4;
  __half*   Ah      = (__half*)ws;   ws += (size_t)NN * 64 * 2;             // 12.8 MB L1 msgs
  __half*   Ah2     = (__half*)ws;   ws += (size_t)NN * 32 * 2;             // 6.4 MB L2 msgs
  float*    Af      = (float*)ws;    ws += (size_t)NN * 4;                  // 400 KB L3 msgs

  // ---- CSR build (deterministic two-pass counting sort) + dis
  k_chist <<<NCH, 256, 0, stream>>>(ei, H);
  k_csum  <<<(NBUK + 255) / 256, 256, 0, stream>>>(H, tot);
  k_bscan <<<1, 1024, 0, stream>>>(tot, boff);
  k_scat  <<<NCH, 1024, 0, stream>>>(ei, H, boff, se);
  k_blocal<<<NBUK, 256, 0, stream>>>(se, boff, rowptr, dis, csr_src);

  // ---- layer 1 GEMM: x @ W1 scaled -> fp16 messages
  k_gemm64_h<<<1250, 256, 0, stream>>>(x, W1, dis, Ah);
  // ---- layer-1 aggregation + tanh + FUSED layer-2 GEMM -> fp16 L2 messages
  k_agg64f<<<NN / 32, 256, 0, stream>>>(rowptr, csr_src, Ah, dis, b1, W2, Ah2);
  // ---- layer-2 aggregation + tanh + FUSED layer-3 GEMM -> fp32 L3 messages
  k_agg32v<<<NN / 32, 256, 0, stream>>>(rowptr, csr_src, Ah2, dis, b2, W3, Af);
  // ---- layer-3 aggregation -> d_out
  k_agg1<<<(NN + 255) / 256, 256, 0, stream>>>(rowptr, csr_src, Af, dis, b3, out);
}

// Round 19
// 247.668 us; speedup vs baseline: 3.1865x; 1.0112x over previous
//
#include <hip/hip_runtime.h>
#include <hip/hip_fp16.h>
#include <math.h>

static constexpr int NN = 100000;   // nodes
static constexpr int NE = 1600000;  // edges
static constexpr int BUCK_SH = 5;   // 32 nodes per bucket
static constexpr int NBUK = NN >> BUCK_SH;   // 3125 (exact)
static constexpr int NCH = 256;              // chunks (one scat block each)
static constexpr int CH = NE / NCH;          // 6250 edges per chunk (exact)

// pass 1: per-chunk bucket histogram H[chunk][bucket] (plain store)
__global__ __launch_bounds__(256)
void k_chist(const int* __restrict__ ei, int* __restrict__ H) {
  __shared__ int h[NBUK];
  for (int i = threadIdx.x; i < NBUK; i += 256) h[i] = 0;
  __syncthreads();
  int chunk = blockIdx.x;
  int start = chunk * CH;
  for (int e = start + threadIdx.x; e < start + CH; e += 256)
    atomicAdd(&h[ei[NE + e] >> BUCK_SH], 1);
  __syncthreads();
  int* Hc = H + chunk * NBUK;
  for (int i = threadIdx.x; i < NBUK; i += 256) Hc[i] = h[i];
}

// pass 2: in-place exclusive prefix over chunks per bucket; totals -> tot
__global__ void k_csum(int* __restrict__ H, int* __restrict__ tot) {
  int b = blockIdx.x * blockDim.x + threadIdx.x;
  if (b >= NBUK) return;
  int acc = 0;
#pragma unroll 4
  for (int c = 0; c < NCH; ++c) {
    int v = H[c * NBUK + b];
    H[c * NBUK + b] = acc;
    acc += v;
  }
  tot[b] = acc;
}

// single-block scan of bucket totals -> boff (exclusive), boff[NBUK]=NE
__global__ __launch_bounds__(1024)
void k_bscan(const int* __restrict__ tot, int* __restrict__ boff) {
  __shared__ int buf[1024];
  __shared__ int s_carry;
  int tid = threadIdx.x;
  if (tid == 0) s_carry = 0;
  __syncthreads();
  for (int base = 0; base < NBUK; base += 1024) {
    int i = base + tid;
    int v = (i < NBUK) ? tot[i] : 0;
    buf[tid] = v;
    __syncthreads();
#pragma unroll
    for (int off = 1; off < 1024; off <<= 1) {
      int t = (tid >= off) ? buf[tid - off] : 0;
      __syncthreads();
      buf[tid] += t;
      __syncthreads();
    }
    int excl = buf[tid] - v;
    int carry = s_carry;
    if (i < NBUK) boff[i] = carry + excl;
    __syncthreads();
    if (tid == 1023) s_carry = carry + buf[1023];
    __syncthreads();
  }
  if (tid == 0) boff[NBUK] = s_carry;   // == NE
}

// pass 3: one block per chunk; LDS cursors; write packed (dstLow5,src) u32
__global__ __launch_bounds__(1024)
void k_scat(const int* __restrict__ ei, const int* __restrict__ H,
            const int* __restrict__ boff, unsigned* __restrict__ se) {
  __shared__ int cur[NBUK];
  int chunk = blockIdx.x;
  const int* Hc = H + chunk * NBUK;
  for (int i = threadIdx.x; i < NBUK; i += 1024) cur[i] = boff[i] + Hc[i];
  __syncthreads();
  int start = chunk * CH;
  for (int e = start + threadIdx.x; e < start + CH; e += 1024) {
    int src = ei[e], dst = ei[NE + e];
    int pos = atomicAdd(&cur[dst >> BUCK_SH], 1);
    se[pos] = ((unsigned)(dst & 31) << 20) | (unsigned)src;   // src < 2^17
  }
}

// one block per bucket: local counting sort -> rowptr, dis, csr_src
__global__ __launch_bounds__(256)
void k_blocal(const unsigned* __restrict__ se, const int* __restrict__ boff,
              int* __restrict__ rowptr, float* __restrict__ dis, int* __restrict__ csr_src) {
  int b = blockIdx.x;
  int base = boff[b], end = boff[b + 1];
  __shared__ int cnt[32], off[32];
  int tid = threadIdx.x;
  if (tid < 32) cnt[tid] = 0;
  __syncthreads();
  for (int k = base + tid; k < end; k += 256)
    atomicAdd(&cnt[se[k] >> 20], 1);
  __syncthreads();
  if (tid == 0) {
    int acc = 0;
#pragma unroll
    for (int i = 0; i < 32; ++i) { off[i] = acc; acc += cnt[i]; }
  }
  __syncthreads();
  if (tid < 32) {
    int node = (b << BUCK_SH) + tid;
    rowptr[node] = base + off[tid];
    dis[node] = rsqrtf(1.0f + (float)cnt[tid]);
    cnt[tid] = 0;                       // reuse as cursor
  }
  if (b == 0 && tid == 64) rowptr[NN] = NE;
  __syncthreads();
  for (int k = base + tid; k < end; k += 256) {
    unsigned e = se[k];
    int dl = e >> 20;
    int pos = base + off[dl] + atomicAdd(&cnt[dl], 1);
    csr_src[pos] = (int)(e & 0xFFFFFu);
  }
}

// GEMM 64->64 (fp32 in), fp16 out. W-column in registers; rows staged in LDS.
__global__ __launch_bounds__(256)
void k_gemm64_h(const float* __restrict__ in, const float* __restrict__ W,
                const float* __restrict__ dis, __half* __restrict__ g) {
  __shared__ float rows[16 * 64];      // 4 KB
  int c = threadIdx.x & 63;
  int wid = threadIdx.x >> 6;          // 4 waves/block
  float Wc[64];
#pragma unroll
  for (int k = 0; k < 64; ++k) Wc[k] = W[k * 64 + c];
  int tiles = NN / 16;                 // 6250
  for (int t = blockIdx.x; t < tiles; t += gridDim.x) {
    int row0 = t * 16;
    __syncthreads();
    ((float4*)rows)[threadIdx.x] = ((const float4*)(in + (size_t)row0 * 64))[threadIdx.x];
    __syncthreads();
#pragma unroll
    for (int r = 0; r < 4; ++r) {
      const float* rp = rows + (wid * 4 + r) * 64;
      float acc = 0.f;
#pragma unroll
      for (int kc = 0; kc < 64; kc += 4) {
        float4 v = *(const float4*)(rp + kc);   // broadcast ds_read_b128
        acc = fmaf(v.x, Wc[kc + 0], acc);
        acc = fmaf(v.y, Wc[kc + 1], acc);
        acc = fmaf(v.z, Wc[kc + 2], acc);
        acc = fmaf(v.w, Wc[kc + 3], acc);
      }
      int row = row0 + wid * 4 + r;
      g[row * 64 + c] = __float2half(acc * dis[row]);
    }
  }
}

// fast tanh: 1 - 2/(e^{2x}+1); saturates correctly
__device__ __forceinline__ float fast_tanh(float x) {
  float e = __expf(2.0f * x);
  return 1.0f - 2.0f / (e + 1.0f);
}

// unpack 8 fp16 (in a float4) and add into two float4 accumulators
__device__ __forceinline__ void upadd8(float4 r, float4& lo, float4& hi) {
  __half2* h = (__half2*)&r;
  float2 f0 = __half22float2(h[0]);
  float2 f1 = __half22float2(h[1]);
  float2 f2 = __half22float2(h[2]);
  float2 f3 = __half22float2(h[3]);
  lo.x += f0.x; lo.y += f0.y; lo.z += f1.x; lo.w += f1.y;
  hi.x += f2.x; hi.y += f2.y; hi.z += f3.x; hi.w += f3.y;
}

// Layer-1 aggregation FUSED with layer-2 GEMM. 128-thread blocks (2 waves,
// 16 nodes) -> 6250 blocks for CU fill. 8 lanes/node, float4/lane, 8-deep.
__global__ __launch_bounds__(128)
void k_agg64f(const int* __restrict__ rowptr, const int* __restrict__ csr_src,
              const __half* __restrict__ g, const float* __restrict__ dis,
              const float* __restrict__ b, const float* __restrict__ W2,
              __half* __restrict__ g2) {
  __shared__ float tile[2][8][68];
  int lane = threadIdx.x & 63;
  int wid = threadIdx.x >> 6;          // 0..1
  int grp = lane >> 3;                 // node slot 0..7
  int cl = lane & 7;                   // channel octet: ch cl*8..cl*8+7
  int node = blockIdx.x * 16 + wid * 8 + grp;

  // W2 column segment for the epilogue
  int c2 = lane & 31;                  // output column 0..31
  int ksub = lane >> 5;                // K-half 0/1
  float Wc[32];
#pragma unroll
  for (int k = 0; k < 32; ++k) Wc[k] = W2[(ksub * 32 + k) * 32 + c2];

  const char* base = (const char*)g;
  float4 l0 = {0,0,0,0}, h0 = {0,0,0,0}, l1 = {0,0,0,0}, h1 = {0,0,0,0};
  float4 l2 = {0,0,0,0}, h2 = {0,0,0,0}, l3 = {0,0,0,0}, h3 = {0,0,0,0};
  {                                    // self loop
    float4 r = *(const float4*)(base + (size_t)node * 128 + cl * 16);
    upadd8(r, l0, h0);
  }
  int k = rowptr[node], end = rowptr[node + 1];
  for (; k + 8 <= end; k += 8) {       // 8 gathers in flight
    int s0 = csr_src[k + 0], s1 = csr_src[k + 1], s2 = csr_src[k + 2], s3 = csr_src[k + 3];
    int s4 = csr_src[k + 4], s5 = csr_src[k + 5], s6 = csr_src[k + 6], s7 = csr_src[k + 7];
    float4 r0 = *(const float4*)(base + (size_t)s0 * 128 + cl * 16);
    float4 r1 = *(const float4*)(base + (size_t)s1 * 128 + cl * 16);
    float4 r2 = *(const float4*)(base + (size_t)s2 * 128 + cl * 16);
    float4 r3 = *(const float4*)(base + (size_t)s3 * 128 + cl * 16);
    float4 r4 = *(const float4*)(base + (size_t)s4 * 128 + cl * 16);
    float4 r5 = *(const float4*)(base + (size_t)s5 * 128 + cl * 16);
    float4 r6 = *(const float4*)(base + (size_t)s6 * 128 + cl * 16);
    float4 r7 = *(const float4*)(base + (size_t)s7 * 128 + cl * 16);
    upadd8(r0, l0, h0); upadd8(r1, l1, h1);
    upadd8(r2, l2, h2); upadd8(r3, l3, h3);
    upadd8(r4, l0, h0); upadd8(r5, l1, h1);
    upadd8(r6, l2, h2); upadd8(r7, l3, h3);
  }
  for (; k + 4 <= end; k += 4) {
    int s0 = csr_src[k], s1 = csr_src[k + 1], s2 = csr_src[k + 2], s3 = csr_src[k + 3];
    float4 r0 = *(const float4*)(base + (size_t)s0 * 128 + cl * 16);
    float4 r1 = *(const float4*)(base + (size_t)s1 * 128 + cl * 16);
    float4 r2 = *(const float4*)(base + (size_t)s2 * 128 + cl * 16);
    float4 r3 = *(const float4*)(base + (size_t)s3 * 128 + cl * 16);
    upadd8(r0, l0, h0); upadd8(r1, l1, h1);
    upadd8(r2, l2, h2); upadd8(r3, l3, h3);
  }
  for (; k < end; ++k) {
    float4 r = *(const float4*)(base + (size_t)csr_src[k] * 128 + cl * 16);
    upadd8(r, l0, h0);
  }
  float d = dis[node];
  float4 blo = *(const float4*)(b + cl * 8);
  float4 bhi = *(const float4*)(b + cl * 8 + 4);
  float4 vl, vh;
  vl.x = ((l0.x + l1.x) + (l2.x + l3.x)) * d + blo.x;
  vl.y = ((l0.y + l1.y) + (l2.y + l3.y)) * d + blo.y;
  vl.z = ((l0.z + l1.z) + (l2.z + l3.z)) * d + blo.z;
  vl.w = ((l0.w + l1.w) + (l2.w + l3.w)) * d + blo.w;
  vh.x = ((h0.x + h1.x) + (h2.x + h3.x)) * d + bhi.x;
  vh.y = ((h0.y + h1.y) + (h2.y + h3.y)) * d + bhi.y;
  vh.z = ((h0.z + h1.z) + (h2.z + h3.z)) * d + bhi.z;
  vh.w = ((h0.w + h1.w) + (h2.w + h3.w)) * d + bhi.w;
  vl.x = fast_tanh(vl.x); vl.y = fast_tanh(vl.y);
  vl.z = fast_tanh(vl.z); vl.w = fast_tanh(vl.w);
  vh.x = fast_tanh(vh.x); vh.y = fast_tanh(vh.y);
  vh.z = fast_tanh(vh.z); vh.w = fast_tanh(vh.w);

  // stash h1 tile in this wave's own LDS region (no barrier needed)
  *(float4*)&tile[wid][grp][cl * 8] = vl;
  *(float4*)&tile[wid][grp][cl * 8 + 4] = vh;

  // layer-2 GEMM on the wave's own 8 rows
  int rbase = blockIdx.x * 16 + wid * 8;
#pragma unroll
  for (int r = 0; r < 8; ++r) {
    const float* rp = &tile[wid][r][ksub * 32];
    float acc = 0.f;
#pragma unroll
    for (int kc = 0; kc < 32; kc += 4) {
      float4 v = *(const float4*)(rp + kc);
      acc = fmaf(v.x, Wc[kc + 0], acc);
      acc = fmaf(v.y, Wc[kc + 1], acc);
      acc = fmaf(v.z, Wc[kc + 2], acc);
      acc = fmaf(v.w, Wc[kc + 3], acc);
    }
    acc += __shfl_down(acc, 32);       // combine K-halves
    int row = rbase + r;
    if (ksub == 0) g2[row * 32 + c2] = __float2half(acc * dis[row]);
  }
}

// Layer-2 aggregation fused with layer-3 GEMM. 128-thread blocks (16 nodes)
// -> 6250 blocks. 8 lanes/node, float2/lane, 8-deep.
__global__ __launch_bounds__(128)
void k_agg32v(const int* __restrict__ rowptr, const int* __restrict__ csr_src,
              const __half* __restrict__ g, const float* __restrict__ dis,
              const float* __restrict__ b, const float* __restrict__ W3,
              float* __restrict__ Af) {
  int lane = threadIdx.x & 63;
  int grp = lane >> 3;                 // node slot 0..7
  int cl = lane & 7;                   // channel quad: ch cl*4..cl*4+3
  int node = blockIdx.x * 16 + (threadIdx.x >> 6) * 8 + grp;
  if (node >= NN) return;
  const char* base = (const char*)g;
  float4 a0 = {0,0,0,0}, a1 = {0,0,0,0}, a2 = {0,0,0,0}, a3 = {0,0,0,0};
  {                                    // self loop
    float2 r = *(const float2*)(base + (size_t)node * 64 + cl * 8);
    __half2* h = (__half2*)&r;
    float2 f0 = __half22float2(h[0]), f1 = __half22float2(h[1]);
    a0.x += f0.x; a0.y += f0.y; a0.z += f1.x; a0.w += f1.y;
  }
  int k = rowptr[node], end = rowptr[node + 1];
  for (; k + 8 <= end; k += 8) {       // 8 gathers in flight
    float2 r0 = *(const float2*)(base + (size_t)csr_src[k + 0] * 64 + cl * 8);
    float2 r1 = *(const float2*)(base + (size_t)csr_src[k + 1] * 64 + cl * 8);
    float2 r2 = *(const float2*)(base + (size_t)csr_src[k + 2] * 64 + cl * 8);
    float2 r3 = *(const float2*)(base + (size_t)csr_src[k + 3] * 64 + cl * 8);
    float2 r4 = *(const float2*)(base + (size_t)csr_src[k + 4] * 64 + cl * 8);
    float2 r5 = *(const float2*)(base + (size_t)csr_src[k + 5] * 64 + cl * 8);
    float2 r6 = *(const float2*)(base + (size_t)csr_src[k + 6] * 64 + cl * 8);
    float2 r7 = *(const float2*)(base + (size_t)csr_src[k + 7] * 64 + cl * 8);
    __half2* h; float2 f;
    h = (__half2*)&r0; f = __half22float2(h[0]); a0.x += f.x; a0.y += f.y;
    f = __half22float2(h[1]); a0.z += f.x; a0.w += f.y;
    h = (__half2*)&r1; f = __half22float2(h[0]); a1.x += f.x; a1.y += f.y;
    f = __half22float2(h[1]); a1.z += f.x; a1.w += f.y;
    h = (__half2*)&r2; f = __half22float2(h[0]); a2.x += f.x; a2.y += f.y;
    f = __half22float2(h[1]); a2.z += f.x; a2.w += f.y;
    h = (__half2*)&r3; f = __half22float2(h[0]); a3.x += f.x; a3.y += f.y;
    f = __half22float2(h[1]); a3.z += f.x; a3.w += f.y;
    h = (__half2*)&r4; f = __half22float2(h[0]); a0.x += f.x; a0.y += f.y;
    f = __half22float2(h[1]); a0.z += f.x; a0.w += f.y;
    h = (__half2*)&r5; f = __half22float2(h[0]); a1.x += f.x; a1.y += f.y;
    f = __half22float2(h[1]); a1.z += f.x; a1.w += f.y;
    h = (__half2*)&r6; f = __half22float2(h[0]); a2.x += f.x; a2.y += f.y;
    f = __half22float2(h[1]); a2.z += f.x; a2.w += f.y;
    h = (__half2*)&r7; f = __half22float2(h[0]); a3.x += f.x; a3.y += f.y;
    f = __half22float2(h[1]); a3.z += f.x; a3.w += f.y;
  }
  for (; k + 4 <= end; k += 4) {
    float2 r0 = *(const float2*)(base + (size_t)csr_src[k + 0] * 64 + cl * 8);
    float2 r1 = *(const float2*)(base + (size_t)csr_src[k + 1] * 64 + cl * 8);
    float2 r2 = *(const float2*)(base + (size_t)csr_src[k + 2] * 64 + cl * 8);
    float2 r3 = *(const float2*)(base + (size_t)csr_src[k + 3] * 64 + cl * 8);
    __half2* h; float2 f;
    h = (__half2*)&r0; f = __half22float2(h[0]); a0.x += f.x; a0.y += f.y;
    f = __half22float2(h[1]); a0.z += f.x; a0.w += f.y;
    h = (__half2*)&r1; f = __half22float2(h[0]); a1.x += f.x; a1.y += f.y;
    f = __half22float2(h[1]); a1.z += f.x; a1.w += f.y;
    h = (__half2*)&r2; f = __half22float2(h[0]); a2.x += f.x; a2.y += f.y;
    f = __half22float2(h[1]); a2.z += f.x; a2.w += f.y;
    h = (__half2*)&r3; f = __half22float2(h[0]); a3.x += f.x; a3.y += f.y;
    f = __half22float2(h[1]); a3.z += f.x; a3.w += f.y;
  }
  for (; k < end; ++k) {
    float2 r = *(const float2*)(base + (size_t)csr_src[k] * 64 + cl * 8);
    __half2* h = (__half2*)&r;
    float2 f0 = __half22float2(h[0]), f1 = __half22float2(h[1]);
    a0.x += f0.x; a0.y += f0.y; a0.z += f1.x; a0.w += f1.y;
  }
  float d = dis[node];
  float4 bb = *(const float4*)(b + cl * 4);
  float4 v;
  v.x = ((a0.x + a1.x) + (a2.x + a3.x)) * d + bb.x;
  v.y = ((a0.y + a1.y) + (a2.y + a3.y)) * d + bb.y;
  v.z = ((a0.z + a1.z) + (a2.z + a3.z)) * d + bb.z;
  v.w = ((a0.w + a1.w) + (a2.w + a3.w)) * d + bb.w;
  v.x = fast_tanh(v.x); v.y = fast_tanh(v.y);
  v.z = fast_tanh(v.z); v.w = fast_tanh(v.w);
  // layer-3 message: dot(h2_row, W3) * dis
  float4 w3 = *(const float4*)(W3 + cl * 4);
  float p = v.x * w3.x + v.y * w3.y + v.z * w3.z + v.w * w3.w;
  p += __shfl_xor(p, 1);
  p += __shfl_xor(p, 2);
  p += __shfl_xor(p, 4);
  if (cl == 0) Af[node] = p * d;
}

// C=1: thread per node, fp32 (tiny).
__global__ void k_agg1(const int* __restrict__ rowptr, const int* __restrict__ csr_src,
                       const float* __restrict__ g, const float* __restrict__ dis,
                       const float* __restrict__ b, float* __restrict__ out) {
  int node = blockIdx.x * blockDim.x + threadIdx.x;
  if (node >= NN) return;
  float a0 = g[node], a1 = 0.f, a2 = 0.f, a3 = 0.f;
  int beg = rowptr[node], end = rowptr[node + 1];
  int k = beg;
  for (; k + 4 <= end; k += 4) {
    float m0 = g[csr_src[k]], m1 = g[csr_src[k + 1]];
    float m2 = g[csr_src[k + 2]], m3 = g[csr_src[k + 3]];
    a0 += m0; a1 += m1; a2 += m2; a3 += m3;
  }
  for (; k < end; ++k) a0 += g[csr_src[k]];
  out[node] = ((a0 + a1) + (a2 + a3)) * dis[node] + b[0];
}

extern "C" void kernel_launch(void* const* d_in, const int* in_sizes, int n_in,
                              void* d_out, int out_size, void* d_ws, size_t ws_size,
                              hipStream_t stream) {
  const float* x  = (const float*)d_in[0];
  const int*   ei = (const int*)d_in[1];
  const float* W1 = (const float*)d_in[2];
  const float* b1 = (const float*)d_in[3];
  const float* W2 = (const float*)d_in[4];
  const float* b2 = (const float*)d_in[5];
  const float* W3 = (const float*)d_in[6];
  const float* b3 = (const float*)d_in[7];
  float* out = (float*)d_out;

  char* ws = (char*)d_ws;
  int*      H       = (int*)ws;      ws += (size_t)NCH * NBUK * 4;          // 3.2 MB
  int*      tot     = (int*)ws;      ws += ((NBUK + 255)/256)*256 * 4;
  int*      boff    = (int*)ws;      ws += ((NBUK + 1 + 255)/256)*256 * 4;
  unsigned* se      = (unsigned*)ws; ws += (size_t)NE * 4;                  // 6.4 MB
  int*      rowptr  = (int*)ws;      ws += ((NN + 1 + 255)/256)*256 * 4;
  int*      csr_src = (int*)ws;      ws += (size_t)NE * 4;                  // 6.4 MB
  float*    dis     = (float*)ws;    ws += ((NN + 255)/256)*256 * 4;
  __half*   Ah      = (__half*)ws;   ws += (size_t)NN * 64 * 2;             // 12.8 MB L1 msgs
  __half*   Ah2     = (__half*)ws;   ws += (size_t)NN * 32 * 2;             // 6.4 MB L2 msgs
  float*    Af      = (float*)ws;    ws += (size_t)NN * 4;                  // 400 KB L3 msgs

  // ---- CSR build (deterministic two-pass counting sort) + dis
  k_chist <<<NCH, 256, 0, stream>>>(ei, H);
  k_csum  <<<(NBUK + 255) / 256, 256, 0, stream>>>(H, tot);
  k_bscan <<<1, 1024, 0, stream>>>(tot, boff);
  k_scat  <<<NCH, 1024, 0, stream>>>(ei, H, boff, se);
  k_blocal<<<NBUK, 256, 0, stream>>>(se, boff, rowptr, dis, csr_src);

  // ---- layer 1 GEMM: x @ W1 scaled -> fp16 messages
  k_gemm64_h<<<1250, 256, 0, stream>>>(x, W1, dis, Ah);
  // ---- layer-1 aggregation + tanh + FUSED layer-2 GEMM -> fp16 L2 messages
  k_agg64f<<<NN / 16, 128, 0, stream>>>(rowptr, csr_src, Ah, dis, b1, W2, Ah2);
  // ---- layer-2 aggregation + tanh + FUSED layer-3 GEMM -> fp32 L3 messages
  k_agg32v<<<NN / 16, 128, 0, stream>>>(rowptr, csr_src, Ah2, dis, b2, W3, Af);
  // ---- layer-3 aggregation -> d_out
  k_agg1<<<(NN + 255) / 256, 256, 0, stream>>>(rowptr, csr_src, Af, dis, b3, out);
}